// Round 3
// baseline (4128.922 us; speedup 1.0000x reference)
//
#include <hip/hip_runtime.h>

typedef __bf16 bf16;
typedef __bf16 bf16x8 __attribute__((ext_vector_type(8)));
typedef float  f32x16 __attribute__((ext_vector_type(16)));

// ---------------- ws layout (bytes) ----------------
#define OFF_RW      0ull                 // rearranged weights, bf16 (12910592 B)
#define OFF_HB      12910592ull          // h double buffer [2][256][512] bf16
#define HB_BYTES    524288ull
#define OFF_CTR     13434880ull          // 8 group counters (64B apart) + device ctr @ +512
#define CTR_BYTES   1024ull
#define OFF_ZX      13435904ull          // zx chunk [4][256 wg][2][64][16] f32 = 8 MB
#define OFF_Y0      21824512ull          // y0 [128][256][512] bf16 = 32 MB
// total ~55.4 MB

// elem offsets into rW (bf16 elems); K-prefix {0,64,576,1088,1600,1616,2128,2640}
#define EO_W0   0
#define EO_U0   131072
#define EO_W1   1179648
#define EO_U1   2228224
#define EO_DW0  3276800
#define EO_DU0  3309568
#define EO_DW1  4358144
#define EO_DU1  5406720

// ---------------- activations ----------------
__device__ __forceinline__ float fsig(float x) {
  x = fminf(fmaxf(x, -30.f), 30.f);
  float e = __builtin_amdgcn_exp2f(x * -1.4426950408889634f);
  return __builtin_amdgcn_rcpf(1.0f + e);
}
__device__ __forceinline__ float ftanh(float x) {
  x = fminf(fmaxf(x, -15.f), 15.f);
  float e = __builtin_amdgcn_exp2f(x * -2.8853900817779268f);
  return (1.0f - e) * __builtin_amdgcn_rcpf(1.0f + e);
}

// ---------------- main persistent kernel ----------------
// grid 256 wgs x 64 thr; wg -> (group g = blk&7 [32 batch rows], nc = blk>>3 [16 h-cols])
// Prologue: each wg rearranges its 1/256 share of all 8 weight matrices into MFMA
// B-fragment order (bf16), then a device-wide counter barrier gates first use.
__global__ void __launch_bounds__(64, 1)
lstm_main(const float* __restrict__ inp,
          const float* __restrict__ eW0, const float* __restrict__ eU0, const float* __restrict__ eb0,
          const float* __restrict__ eW1, const float* __restrict__ eU1, const float* __restrict__ eb1,
          const float* __restrict__ dW0, const float* __restrict__ dU0, const float* __restrict__ db0,
          const float* __restrict__ dW1, const float* __restrict__ dU1, const float* __restrict__ db1,
          const float* __restrict__ fcW, const float* __restrict__ fcb,
          unsigned char* __restrict__ ws, float* __restrict__ out)
{
  __shared__ __align__(16) unsigned char smem[65536];

  const int wgid = blockIdx.x;
  const int g    = wgid & 7;
  const int nc   = wgid >> 3;
  const int lane = threadIdx.x;
  const int rowbase = g * 32;
  const int col32 = lane & 31;
  const int khalf = lane >> 5;
  const int half  = col32 >> 4;
  const int rowA  = rowbase + col32;

  const bf16* rW = reinterpret_cast<const bf16*>(ws + OFF_RW);
  bf16* hb  = reinterpret_cast<bf16*>(ws + OFF_HB);
  unsigned* gctr = reinterpret_cast<unsigned*>(ws + OFF_CTR) + g * 16;   // 64B apart
  unsigned* dctr = reinterpret_cast<unsigned*>(ws + OFF_CTR) + 128;      // own line
  float* zx = reinterpret_cast<float*>(ws + OFF_ZX);
  bf16* y0  = reinterpret_cast<bf16*>(ws + OFF_Y0);

  unsigned depoch = 0;
  auto dbarrier = [&]() {
    depoch++;
    __builtin_amdgcn_fence(__ATOMIC_RELEASE, "agent");
    if (lane == 0) __hip_atomic_fetch_add(dctr, 1u, __ATOMIC_RELAXED, __HIP_MEMORY_SCOPE_AGENT);
    const unsigned tgt = depoch * 256u;
    while (__hip_atomic_load(dctr, __ATOMIC_RELAXED, __HIP_MEMORY_SCOPE_AGENT) < tgt)
      __builtin_amdgcn_s_sleep(1);
    __builtin_amdgcn_fence(__ATOMIC_ACQUIRE, "agent");
  };

  // ================= inline prep: weights -> MFMA B-fragment order =================
  // rW unit layout: [mat][nc(32)][ntile(2)][kstep(K/16)][ln(64)] of 8 bf16 (16B)
  // B-frag (32x32x16): lane holds B[k = kstep*16 + (ln>>5)*8 + j][col = ln&31]
  // col -> zcol: gate = ntile*2 + (col>>4); zcol = gate*512 + nc*16 + (col&15)
  {
    const int Ks[8]    = {64, 512, 512, 512, 16, 512, 512, 512};
    const int pref[8]  = {0, 64, 576, 1088, 1600, 1616, 2128, 2640};
    const float* srcs[8] = {eW0, eU0, eW1, eU1, dW0, dU0, dW1, dU1};
    bf16* rWw = reinterpret_cast<bf16*>(ws + OFF_RW);
    // total units = 806912 = 256 wgs * 3152
    for (int base = 0; base < 3152; base += 64) {
      if (base + lane < 3152) {
        unsigned uid = (unsigned)wgid * 3152u + (unsigned)(base + lane);
        int m = 0;
#pragma unroll
        for (int i = 1; i < 8; ++i) if (uid >= (unsigned)pref[i] * 256u) m = i;
        unsigned local = uid - (unsigned)pref[m] * 256u;
        const int K = Ks[m];
        const unsigned perNC   = (unsigned)K * 8u;
        const unsigned ncb     = local / perNC;
        const unsigned r0      = local % perNC;
        const unsigned perTile = perNC >> 1;
        const unsigned ntile   = r0 / perTile;
        const unsigned r1      = r0 % perTile;
        const unsigned kstep   = r1 >> 6;
        const unsigned ln      = r1 & 63u;
        const unsigned c32     = ln & 31u;
        const unsigned gate    = ntile * 2u + (c32 >> 4);
        const unsigned zcol    = gate * 512u + ncb * 16u + (c32 & 15u);
        const unsigned kb      = kstep * 16u + (ln >> 5) * 8u;
        const float* s = srcs[m];
        bf16x8 v;
#pragma unroll
        for (int j = 0; j < 8; ++j) v[j] = (bf16)s[(size_t)(kb + j) * 2048u + zcol];
        reinterpret_cast<bf16x8*>(rWw)[uid] = v;
      }
    }
  }
  dbarrier();   // all weights converted before any wg reads rW

  float c[16];
#pragma unroll
  for (int i = 0; i < 16; ++i) c[i] = 0.f;
  unsigned epoch = 0;
  int cur = 0;

  auto load_lds = [&](const bf16* src) {
    __syncthreads();
#pragma unroll 4
    for (int i = 0; i < 64; ++i) {
      *reinterpret_cast<bf16x8*>(smem + (i * 64 + lane) * 16) =
        *reinterpret_cast<const bf16x8*>(src + (size_t)(i * 64 + lane) * 8);
    }
    __syncthreads();
  };

  auto barrier = [&]() {
    epoch++;
    __builtin_amdgcn_fence(__ATOMIC_RELEASE, "agent");
    if (lane == 0) __hip_atomic_fetch_add(gctr, 1u, __ATOMIC_RELAXED, __HIP_MEMORY_SCOPE_AGENT);
    const unsigned tgt = epoch * 32u;
    while (__hip_atomic_load(gctr, __ATOMIC_RELAXED, __HIP_MEMORY_SCOPE_AGENT) < tgt)
      __builtin_amdgcn_s_sleep(1);
    __builtin_amdgcn_fence(__ATOMIC_ACQUIRE, "agent");
  };

  auto rec512 = [&](const bf16* hsrc, f32x16& a0, f32x16& a1) {
#pragma unroll 8
    for (int ks = 0; ks < 32; ++ks) {
      bf16x8 af  = *reinterpret_cast<const bf16x8*>(hsrc + (size_t)rowA * 512 + ks * 16 + khalf * 8);
      bf16x8 bl0 = *reinterpret_cast<const bf16x8*>(smem + (ks * 64 + lane) * 16);
      bf16x8 bl1 = *reinterpret_cast<const bf16x8*>(smem + 32768 + (ks * 64 + lane) * 16);
      a0 = __builtin_amdgcn_mfma_f32_32x32x16_bf16(af, bl0, a0, 0, 0, 0);
      a1 = __builtin_amdgcn_mfma_f32_32x32x16_bf16(af, bl1, a1, 0, 0, 0);
    }
  };

  // gates: acc0 = [i|f] cols, acc1 = [g|o] cols; partner gate via shfl_xor 16.
  // C-layout: col=lane&31, row=(r&3)+8*(r>>2)+4*(lane>>5). Lanes col<16 and col>=16
  // compute duplicate cells (consistent); only col<16 lanes store.
  auto gates = [&](const f32x16& a0, const f32x16& a1, bf16* hdst, bf16* ydst) {
#pragma unroll
    for (int r = 0; r < 16; ++r) {
      float v0 = a0[r], v1 = a1[r];
      float v0x = __shfl_xor(v0, 16, 64);
      float v1x = __shfl_xor(v1, 16, 64);
      float iv = half ? v0x : v0;
      float fv = half ? v0  : v0x;
      float gv = half ? v1x : v1;
      float ov = half ? v1  : v1x;
      float cn = fsig(fv) * c[r] + fsig(iv) * ftanh(gv);
      c[r] = cn;
      float hv = fsig(ov) * ftanh(cn);
      if (half == 0) {
        int row = (r & 3) + 8 * (r >> 2) + 4 * khalf;
        size_t idx = (size_t)(rowbase + row) * 512 + nc * 16 + col32;
        hdst[idx] = (bf16)hv;
        if (ydst) ydst[idx] = (bf16)hv;
      }
    }
  };

  // ================= encoder layers =================
  for (int ph = 0; ph < 2; ++ph) {
    const bf16* rU = rW + (ph == 0 ? EO_U0 : EO_U1) + (size_t)nc * 32768;
    const bf16* rX = (ph == 0) ? (rW + EO_W0 + (size_t)nc * 4096)
                               : (rW + EO_W1 + (size_t)nc * 32768);
    const int kxs = (ph == 0) ? 4 : 32;
    const float* bias = (ph == 0) ? eb0 : eb1;

    load_lds(rU);
    const float bz0 = bias[(col32 >> 4) * 512 + nc * 16 + (col32 & 15)];
    const float bz1 = bias[(2 + (col32 >> 4)) * 512 + nc * 16 + (col32 & 15)];

    for (int ch = 0; ch < 32; ++ch) {
      // ---- x-projection for 4 timesteps (zx = X@Wx + b), acc in C-layout ----
      f32x16 acc[4][2];
#pragma unroll
      for (int tt = 0; tt < 4; ++tt) {
#pragma unroll
        for (int r = 0; r < 16; ++r) { acc[tt][0][r] = bz0; acc[tt][1][r] = bz1; }
      }
      for (int ks = 0; ks < kxs; ++ks) {
        bf16x8 bg0 = *reinterpret_cast<const bf16x8*>(rX + (size_t)(0 * kxs + ks) * 512 + lane * 8);
        bf16x8 bg1 = *reinterpret_cast<const bf16x8*>(rX + (size_t)(1 * kxs + ks) * 512 + lane * 8);
#pragma unroll
        for (int tt = 0; tt < 4; ++tt) {
          const int t = ch * 4 + tt;
          bf16x8 af;
          if (ph == 0) {
            const float* p = inp + ((size_t)rowA * 128 + t) * 64 + ks * 16 + khalf * 8;
#pragma unroll
            for (int j = 0; j < 8; ++j) af[j] = (bf16)p[j];
          } else {
            af = *reinterpret_cast<const bf16x8*>(y0 + ((size_t)t * 256 + rowA) * 512 + ks * 16 + khalf * 8);
          }
          acc[tt][0] = __builtin_amdgcn_mfma_f32_32x32x16_bf16(af, bg0, acc[tt][0], 0, 0, 0);
          acc[tt][1] = __builtin_amdgcn_mfma_f32_32x32x16_bf16(af, bg1, acc[tt][1], 0, 0, 0);
        }
      }
#pragma unroll
      for (int tt = 0; tt < 4; ++tt) {
        float* zp = zx + ((size_t)tt * 256 + wgid) * 2048 + lane * 16;
        *reinterpret_cast<f32x16*>(zp)        = acc[tt][0];
        *reinterpret_cast<f32x16*>(zp + 1024) = acc[tt][1];
      }
      // ---- 4 recurrent steps ----
#pragma unroll 1
      for (int tt = 0; tt < 4; ++tt) {
        const int t = ch * 4 + tt;
        const float* zp = zx + ((size_t)tt * 256 + wgid) * 2048 + lane * 16;
        f32x16 a0 = *reinterpret_cast<const f32x16*>(zp);
        f32x16 a1 = *reinterpret_cast<const f32x16*>(zp + 1024);
        const bf16* hsrc = hb + (size_t)cur * 131072;
        bf16* hdst = hb + (size_t)(cur ^ 1) * 131072;
        rec512(hsrc, a0, a1);
        gates(a0, a1, hdst, (ph == 0) ? (y0 + (size_t)t * 131072) : nullptr);
        barrier();
        cur ^= 1;
      }
    }
  }

  // ================= decoder layer 0 (1 step, Kx=16) =================
  {
    load_lds(rW + EO_DU0 + (size_t)nc * 32768);
    const bf16* rX = rW + EO_DW0 + (size_t)nc * 1024;
    const float bz0 = db0[(col32 >> 4) * 512 + nc * 16 + (col32 & 15)];
    const float bz1 = db0[(2 + (col32 >> 4)) * 512 + nc * 16 + (col32 & 15)];
    f32x16 a0, a1;
#pragma unroll
    for (int r = 0; r < 16; ++r) { a0[r] = bz0; a1[r] = bz1; }
    bf16x8 bg0 = *reinterpret_cast<const bf16x8*>(rX + lane * 8);
    bf16x8 bg1 = *reinterpret_cast<const bf16x8*>(rX + 512 + lane * 8);
    bf16x8 af;
    {
      const float* p = inp + ((size_t)rowA * 128 + 127) * 64 + khalf * 8;  // dec_in = inp[:, -1, :16]
#pragma unroll
      for (int j = 0; j < 8; ++j) af[j] = (bf16)p[j];
    }
    a0 = __builtin_amdgcn_mfma_f32_32x32x16_bf16(af, bg0, a0, 0, 0, 0);
    a1 = __builtin_amdgcn_mfma_f32_32x32x16_bf16(af, bg1, a1, 0, 0, 0);
    const bf16* hsrc = hb + (size_t)cur * 131072;
    bf16* hdst = hb + (size_t)(cur ^ 1) * 131072;
    rec512(hsrc, a0, a1);
    gates(a0, a1, hdst, nullptr);
    barrier();
    cur ^= 1;
  }

  // ================= decoder layer 1 (1 step; x input == hd0 == d0) =================
  {
    load_lds(rW + EO_DU1 + (size_t)nc * 32768);
    const bf16* rXW = rW + EO_DW1 + (size_t)nc * 32768;
    const float bz0 = db1[(col32 >> 4) * 512 + nc * 16 + (col32 & 15)];
    const float bz1 = db1[(2 + (col32 >> 4)) * 512 + nc * 16 + (col32 & 15)];
    f32x16 a0, a1;
#pragma unroll
    for (int r = 0; r < 16; ++r) { a0[r] = bz0; a1[r] = bz1; }
    const bf16* hsrc = hb + (size_t)cur * 131072;   // d0
    bf16* hdst = hb + (size_t)(cur ^ 1) * 131072;
#pragma unroll 4
    for (int ks = 0; ks < 32; ++ks) {
      bf16x8 af  = *reinterpret_cast<const bf16x8*>(hsrc + (size_t)rowA * 512 + ks * 16 + khalf * 8);
      bf16x8 bg0 = *reinterpret_cast<const bf16x8*>(rXW + (size_t)(0 * 32 + ks) * 512 + lane * 8);
      bf16x8 bg1 = *reinterpret_cast<const bf16x8*>(rXW + (size_t)(1 * 32 + ks) * 512 + lane * 8);
      bf16x8 bl0 = *reinterpret_cast<const bf16x8*>(smem + (ks * 64 + lane) * 16);
      bf16x8 bl1 = *reinterpret_cast<const bf16x8*>(smem + 32768 + (ks * 64 + lane) * 16);
      a0 = __builtin_amdgcn_mfma_f32_32x32x16_bf16(af, bg0, a0, 0, 0, 0);
      a0 = __builtin_amdgcn_mfma_f32_32x32x16_bf16(af, bl0, a0, 0, 0, 0);
      a1 = __builtin_amdgcn_mfma_f32_32x32x16_bf16(af, bg1, a1, 0, 0, 0);
      a1 = __builtin_amdgcn_mfma_f32_32x32x16_bf16(af, bl1, a1, 0, 0, 0);
    }
    gates(a0, a1, hdst, nullptr);
    barrier();
    cur ^= 1;
  }

  // wait for ALL groups: FC reads row wgid, produced by group (wgid>>5) != (wgid&7)
  dbarrier();

  // ================= FC + tile(48) : wg handles batch row = wgid =================
  {
    const bf16* d1 = hb + (size_t)cur * 131072 + (size_t)wgid * 512;
    bf16x8 xv = *reinterpret_cast<const bf16x8*>(d1 + lane * 8);
    float part[16];
#pragma unroll
    for (int o = 0; o < 16; ++o) part[o] = 0.f;
#pragma unroll
    for (int j = 0; j < 8; ++j) {
      float x = (float)xv[j];
      const float* wrow = fcW + (size_t)(lane * 8 + j) * 16;
#pragma unroll
      for (int o = 0; o < 16; ++o) part[o] = fmaf(x, wrow[o], part[o]);
    }
    __syncthreads();
    float* fl = reinterpret_cast<float*>(smem);
#pragma unroll
    for (int o = 0; o < 16; ++o) fl[lane * 17 + o] = part[o];
    __syncthreads();
    if (lane < 16) {
      float s = fcb[lane];
      for (int l = 0; l < 64; ++l) s += fl[l * 17 + lane];
      fl[64 * 17 + lane] = s;
    }
    __syncthreads();
    // each 16-lane quad writes one timestep per rep: t = rep*4 + quad covers 0..47
    const int quad = lane >> 4;
    const float val = fl[64 * 17 + (lane & 15)];
    float* orow = out + (size_t)wgid * 768;
#pragma unroll
    for (int rep = 0; rep < 12; ++rep) {
      orow[(rep * 4 + quad) * 16 + (lane & 15)] = val;
    }
  }
}

// ---------------- launch ----------------
extern "C" void kernel_launch(void* const* d_in, const int* in_sizes, int n_in,
                              void* d_out, int out_size, void* d_ws, size_t ws_size,
                              hipStream_t stream) {
  (void)in_sizes; (void)n_in; (void)out_size; (void)ws_size;
  const float* inp = (const float*)d_in[0];
  // d_in[1] = future_seq_len (48, hardcoded)
  const float* eW0 = (const float*)d_in[2];
  const float* eU0 = (const float*)d_in[3];
  const float* eb0 = (const float*)d_in[4];
  const float* eW1 = (const float*)d_in[5];
  const float* eU1 = (const float*)d_in[6];
  const float* eb1 = (const float*)d_in[7];
  const float* dW0 = (const float*)d_in[8];
  const float* dU0 = (const float*)d_in[9];
  const float* db0 = (const float*)d_in[10];
  const float* dW1 = (const float*)d_in[11];
  const float* dU1 = (const float*)d_in[12];
  const float* db1 = (const float*)d_in[13];
  const float* fcW = (const float*)d_in[14];
  const float* fcb = (const float*)d_in[15];
  unsigned char* ws = (unsigned char*)d_ws;
  float* out = (float*)d_out;

  // zero h double-buffer + barrier counters (contiguous region)
  hipMemsetAsync(ws + OFF_HB, 0, HB_BYTES + CTR_BYTES, stream);

  lstm_main<<<dim3(256), dim3(64), 0, stream>>>(
      inp, eW0, eU0, eb0, eW1, eU1, eb1, dW0, dU0, db0, dW1, dU1, db1,
      fcW, fcb, ws, out);
}

// Round 4
// 3365.396 us; speedup vs baseline: 1.2269x; 1.2269x over previous
//
#include <hip/hip_runtime.h>

typedef __bf16 bf16;
typedef __bf16 bf16x8 __attribute__((ext_vector_type(8)));
typedef float  f32x16 __attribute__((ext_vector_type(16)));
typedef unsigned int u32x4 __attribute__((ext_vector_type(4)));

// ---------------- ws layout (bytes) ----------------
#define OFF_RW      0ull                 // rearranged weights, bf16 (12910592 B)
#define OFF_HB      12910592ull          // h double buffer [2][256][512] bf16
#define HB_BYTES    524288ull
#define OFF_CTR     13434880ull          // 8 group ctrs (64B apart) + device ctr @ +512
#define CTR_BYTES   1024ull
#define OFF_Y0      21824512ull          // y0 [128][256][512] bf16 = 32 MB

// elem offsets into rW (bf16 elems); K-prefix {0,64,576,1088,1600,1616,2128,2640}
#define EO_W0   0
#define EO_U0   131072
#define EO_W1   1179648
#define EO_U1   2228224
#define EO_DW0  3276800
#define EO_DU0  3309568
#define EO_DW1  4358144
#define EO_DU1  5406720   // holds (dW1 + dU1) combined (dec1: x == h_init)

// ---------------- activations ----------------
__device__ __forceinline__ float fsig(float x) {
  x = fminf(fmaxf(x, -30.f), 30.f);
  float e = __builtin_amdgcn_exp2f(x * -1.4426950408889634f);
  return __builtin_amdgcn_rcpf(1.0f + e);
}
__device__ __forceinline__ float ftanh(float x) {
  x = fminf(fmaxf(x, -15.f), 15.f);
  float e = __builtin_amdgcn_exp2f(x * -2.8853900817779268f);
  return (1.0f - e) * __builtin_amdgcn_rcpf(1.0f + e);
}

// sc1 (agent-coherent / LLC) memory ops
#define HLOAD16(dst, addr) \
  asm volatile("global_load_dwordx4 %0, %1, off sc1" : "=v"(dst) : "v"(addr) : "memory")
#define HSTORE2(addr, val) \
  asm volatile("global_store_short %0, %1, off sc1" :: "v"(addr), "v"(val) : "memory")
#define HSTORE16(addr, val) \
  asm volatile("global_store_dwordx4 %0, %1, off sc1" :: "v"(addr), "v"(val) : "memory")
#define WAIT_VM(n) asm volatile("s_waitcnt vmcnt(" #n ")" ::: "memory")

// ---------------- main persistent kernel ----------------
// grid 256 wgs x 64 thr; wg -> (group g = blk&7 [32 batch rows], nc = blk>>3 [16 h-cols])
__global__ void __launch_bounds__(64, 1)
lstm_main(const float* __restrict__ inp,
          const float* __restrict__ eW0, const float* __restrict__ eU0, const float* __restrict__ eb0,
          const float* __restrict__ eW1, const float* __restrict__ eU1, const float* __restrict__ eb1,
          const float* __restrict__ dW0, const float* __restrict__ dU0, const float* __restrict__ db0,
          const float* __restrict__ dW1, const float* __restrict__ dU1, const float* __restrict__ db1,
          const float* __restrict__ fcW, const float* __restrict__ fcb,
          unsigned char* __restrict__ ws, float* __restrict__ out)
{
  __shared__ __align__(16) unsigned char smem[65536];

  const int wgid = blockIdx.x;
  const int g    = wgid & 7;
  const int nc   = wgid >> 3;
  const int lane = threadIdx.x;
  const int rowbase = g * 32;
  const int col32 = lane & 31;
  const int khalf = lane >> 5;
  const int half  = col32 >> 4;
  const int rowA  = rowbase + col32;

  const bf16* rW = reinterpret_cast<const bf16*>(ws + OFF_RW);
  bf16* hb  = reinterpret_cast<bf16*>(ws + OFF_HB);
  unsigned* gctr = reinterpret_cast<unsigned*>(ws + OFF_CTR) + g * 16;
  unsigned* dctr = reinterpret_cast<unsigned*>(ws + OFF_CTR) + 128;
  bf16* y0  = reinterpret_cast<bf16*>(ws + OFF_Y0);

  unsigned depoch = 0;
  auto dbarrier = [&]() {
    depoch++;
    WAIT_VM(0);
    if (lane == 0) __hip_atomic_fetch_add(dctr, 1u, __ATOMIC_RELAXED, __HIP_MEMORY_SCOPE_AGENT);
    const unsigned tgt = depoch * 256u;
    while (__hip_atomic_load(dctr, __ATOMIC_RELAXED, __HIP_MEMORY_SCOPE_AGENT) < tgt)
      __builtin_amdgcn_s_sleep(1);
  };

  // ================= inline prep: weights -> MFMA B-fragment order (sc1 stores) ====
  {
    const int Ks[8]    = {64, 512, 512, 512, 16, 512, 512, 512};
    const int pref[8]  = {0, 64, 576, 1088, 1600, 1616, 2128, 2640};
    const float* srcs[8] = {eW0, eU0, eW1, eU1, dW0, dU0, dW1, dU1};
    bf16* rWw = reinterpret_cast<bf16*>(ws + OFF_RW);
    for (int base = 0; base < 3152; base += 64) {
      if (base + lane < 3152) {
        unsigned uid = (unsigned)wgid * 3152u + (unsigned)(base + lane);
        int m = 0;
#pragma unroll
        for (int i = 1; i < 8; ++i) if (uid >= (unsigned)pref[i] * 256u) m = i;
        unsigned local = uid - (unsigned)pref[m] * 256u;
        const int K = Ks[m];
        const unsigned perNC   = (unsigned)K * 8u;
        const unsigned ncb     = local / perNC;
        const unsigned r0      = local % perNC;
        const unsigned perTile = perNC >> 1;
        const unsigned ntile   = r0 / perTile;
        const unsigned r1      = r0 % perTile;
        const unsigned kstep   = r1 >> 6;
        const unsigned ln      = r1 & 63u;
        const unsigned c32     = ln & 31u;
        const unsigned gate    = ntile * 2u + (c32 >> 4);
        const unsigned zcol    = gate * 512u + ncb * 16u + (c32 & 15u);
        const unsigned kb      = kstep * 16u + (ln >> 5) * 8u;
        const float* s = srcs[m];
        bf16x8 v;
#pragma unroll
        for (int j = 0; j < 8; ++j) {
          float vj = s[(size_t)(kb + j) * 2048u + zcol];
          if (m == 7) vj += dW1[(size_t)(kb + j) * 2048u + zcol];  // dec1 combined W+U
          v[j] = (bf16)vj;
        }
        u32x4 bits = __builtin_bit_cast(u32x4, v);
        HSTORE16(rWw + (size_t)uid * 8, bits);
      }
    }
  }
  dbarrier();
  __builtin_amdgcn_fence(__ATOMIC_ACQUIRE, "agent");  // one-time: purge stale L2 lines

  // bias registers (gate pair [i|f] -> a, [g|o] -> b)
  const int bcol = nc * 16 + (col32 & 15);
  const int bg_  = col32 >> 4;
  const float bE0a = eb0[bg_ * 512 + bcol], bE0b = eb0[(2 + bg_) * 512 + bcol];
  const float bE1a = eb1[bg_ * 512 + bcol], bE1b = eb1[(2 + bg_) * 512 + bcol];
  const float bD0a = db0[bg_ * 512 + bcol], bD0b = db0[(2 + bg_) * 512 + bcol];
  const float bD1a = db1[bg_ * 512 + bcol], bD1b = db1[(2 + bg_) * 512 + bcol];

  float c[16];
#pragma unroll
  for (int i = 0; i < 16; ++i) c[i] = 0.f;
  unsigned epoch = 0;
  int cur = 0;

  auto load_lds = [&](const bf16* src) {
#pragma unroll 8
    for (int i = 0; i < 64; ++i) {
      *reinterpret_cast<bf16x8*>(smem + (i * 64 + lane) * 16) =
        *reinterpret_cast<const bf16x8*>(src + (size_t)(i * 64 + lane) * 8);
    }
    __syncthreads();
  };

  auto arrive = [&]() {
    epoch++;
    WAIT_VM(0);
    if (lane == 0) __hip_atomic_fetch_add(gctr, 1u, __ATOMIC_RELAXED, __HIP_MEMORY_SCOPE_AGENT);
  };
  auto wait_grp = [&]() {
    const unsigned tgt = epoch * 32u;
    while (__hip_atomic_load(gctr, __ATOMIC_RELAXED, __HIP_MEMORY_SCOPE_AGENT) < tgt)
      __builtin_amdgcn_s_sleep(1);
  };

  // recurrent GEMM step: sc1 h loads, 2x8 pipelined batches, MFMA vs LDS U-slice
  auto rec512 = [&](const bf16* hsrc, f32x16& a0, f32x16& a1) {
    const char* hp = (const char*)(hsrc + (size_t)rowA * 512 + khalf * 8);
    u32x4 hreg[16];
#pragma unroll
    for (int i = 0; i < 16; ++i) HLOAD16(hreg[i], hp + i * 32);
#pragma unroll
    for (int b = 0; b < 4; ++b) {
      if (b < 3) { WAIT_VM(8); } else { WAIT_VM(0); }
      const int sb = (b & 1) * 8;
#pragma unroll
      for (int i = 0; i < 8; ++i) {
        const int ks = b * 8 + i;
        bf16x8 af  = __builtin_bit_cast(bf16x8, hreg[sb + i]);
        bf16x8 bl0 = *reinterpret_cast<const bf16x8*>(smem + (ks * 64 + lane) * 16);
        bf16x8 bl1 = *reinterpret_cast<const bf16x8*>(smem + 32768 + (ks * 64 + lane) * 16);
        a0 = __builtin_amdgcn_mfma_f32_32x32x16_bf16(af, bl0, a0, 0, 0, 0);
        a1 = __builtin_amdgcn_mfma_f32_32x32x16_bf16(af, bl1, a1, 0, 0, 0);
      }
      if (b < 2) {
#pragma unroll
        for (int i = 0; i < 8; ++i) HLOAD16(hreg[sb + i], hp + (16 + b * 8 + i) * 32);
      }
    }
  };

  // gates: a0 = [i|f] cols, a1 = [g|o] cols; partner gate via shfl_xor 16.
  auto gates = [&](const f32x16& a0, const f32x16& a1, bf16* hdst, bf16* ydst) {
#pragma unroll
    for (int r = 0; r < 16; ++r) {
      float v0 = a0[r], v1 = a1[r];
      float v0x = __shfl_xor(v0, 16, 64);
      float v1x = __shfl_xor(v1, 16, 64);
      float iv = half ? v0x : v0;
      float fv = half ? v0  : v0x;
      float gv = half ? v1x : v1;
      float ov = half ? v1  : v1x;
      float cn = fsig(fv) * c[r] + fsig(iv) * ftanh(gv);
      c[r] = cn;
      float hv = fsig(ov) * ftanh(cn);
      if (half == 0) {
        int row = (r & 3) + 8 * (r >> 2) + 4 * khalf;
        size_t idx = (size_t)(rowbase + row) * 512 + nc * 16 + col32;
        unsigned short hbits = __builtin_bit_cast(unsigned short, (bf16)hv);
        HSTORE2(hdst + idx, hbits);
        if (ydst) HSTORE2(ydst + idx, hbits);
      }
    }
  };

  // x-projection for a 4-step chunk; acc stays in VGPRs
  auto xproj = [&](int isPh1, int ch, const bf16* rX, int kxs, float bza, float bzb,
                   f32x16 (&acc)[4][2]) {
#pragma unroll
    for (int tt = 0; tt < 4; ++tt)
#pragma unroll
      for (int r = 0; r < 16; ++r) { acc[tt][0][r] = bza; acc[tt][1][r] = bzb; }
    for (int ks = 0; ks < kxs; ++ks) {
      bf16x8 bg0 = *reinterpret_cast<const bf16x8*>(rX + (size_t)ks * 512 + lane * 8);
      bf16x8 bg1 = *reinterpret_cast<const bf16x8*>(rX + (size_t)(kxs + ks) * 512 + lane * 8);
#pragma unroll
      for (int tt = 0; tt < 4; ++tt) {
        const int t = ch * 4 + tt;
        bf16x8 af;
        if (isPh1) {
          af = *reinterpret_cast<const bf16x8*>(y0 + ((size_t)t * 256 + rowA) * 512 + ks * 16 + khalf * 8);
        } else {
          const float* p = inp + ((size_t)rowA * 128 + t) * 64 + ks * 16 + khalf * 8;
#pragma unroll
          for (int j = 0; j < 8; ++j) af[j] = (bf16)p[j];
        }
        acc[tt][0] = __builtin_amdgcn_mfma_f32_32x32x16_bf16(af, bg0, acc[tt][0], 0, 0, 0);
        acc[tt][1] = __builtin_amdgcn_mfma_f32_32x32x16_bf16(af, bg1, acc[tt][1], 0, 0, 0);
      }
    }
  };

  const bf16* rU0e = rW + EO_U0 + (size_t)nc * 32768;
  const bf16* rU1e = rW + EO_U1 + (size_t)nc * 32768;
  const bf16* rX0e = rW + EO_W0 + (size_t)nc * 4096;
  const bf16* rX1e = rW + EO_W1 + (size_t)nc * 32768;

  // ================= encoder layers (overlapped x-proj / weight staging) ==========
  f32x16 acc[4][2];
  load_lds(rU0e);
  xproj(0, 0, rX0e, 4, bE0a, bE0b, acc);
  for (int ph = 0; ph < 2; ++ph) {
    for (int ch = 0; ch < 32; ++ch) {
#pragma unroll
      for (int tt = 0; tt < 4; ++tt) {
        const bf16* hsrc = hb + (size_t)cur * 131072;
        bf16* hdst = hb + (size_t)(cur ^ 1) * 131072;
        rec512(hsrc, acc[tt][0], acc[tt][1]);
        gates(acc[tt][0], acc[tt][1], hdst,
              (ph == 0) ? (y0 + (size_t)(ch * 4 + tt) * 131072) : nullptr);
        arrive();
        if (tt == 3) {                       // fill the barrier window
          if (ch < 31) {
            if (ph == 0) xproj(0, ch + 1, rX0e, 4,  bE0a, bE0b, acc);
            else         xproj(1, ch + 1, rX1e, 32, bE1a, bE1b, acc);
          } else if (ph == 0) {
            load_lds(rU1e);
            xproj(1, 0, rX1e, 32, bE1a, bE1b, acc);
          } else {
            load_lds(rW + EO_DU0 + (size_t)nc * 32768);   // stage decoder0 U
          }
        }
        wait_grp();
        cur ^= 1;
      }
    }
  }

  // ================= decoder layer 0 (1 step, Kx=16) =================
  {
    f32x16 a0, a1;
#pragma unroll
    for (int r = 0; r < 16; ++r) { a0[r] = bD0a; a1[r] = bD0b; }
    const bf16* rX = rW + EO_DW0 + (size_t)nc * 1024;
    bf16x8 bg0 = *reinterpret_cast<const bf16x8*>(rX + lane * 8);
    bf16x8 bg1 = *reinterpret_cast<const bf16x8*>(rX + 512 + lane * 8);
    bf16x8 af;
    const float* p = inp + ((size_t)rowA * 128 + 127) * 64 + khalf * 8;  // inp[:,-1,:16]
#pragma unroll
    for (int j = 0; j < 8; ++j) af[j] = (bf16)p[j];
    a0 = __builtin_amdgcn_mfma_f32_32x32x16_bf16(af, bg0, a0, 0, 0, 0);
    a1 = __builtin_amdgcn_mfma_f32_32x32x16_bf16(af, bg1, a1, 0, 0, 0);
    rec512(hb + (size_t)cur * 131072, a0, a1);
    gates(a0, a1, hb + (size_t)(cur ^ 1) * 131072, nullptr);
    arrive();
    load_lds(rW + EO_DU1 + (size_t)nc * 32768);   // combined (dW1+dU1)
    wait_grp();
    cur ^= 1;
  }

  // ================= decoder layer 1: z = d0 @ (dW1+dU1) + b (x == h_init) ========
  {
    f32x16 a0, a1;
#pragma unroll
    for (int r = 0; r < 16; ++r) { a0[r] = bD1a; a1[r] = bD1b; }
    rec512(hb + (size_t)cur * 131072, a0, a1);
    gates(a0, a1, hb + (size_t)(cur ^ 1) * 131072, nullptr);
    arrive();
    wait_grp();
    cur ^= 1;
  }

  // cross-group visibility for FC (wg reads batch row wgid, produced by group wgid>>5)
  dbarrier();

  // ================= FC + tile(48) : wg handles batch row = wgid =================
  {
    const bf16* d1 = hb + (size_t)cur * 131072 + (size_t)wgid * 512;
    u32x4 dreg;
    HLOAD16(dreg, d1 + lane * 8);
    WAIT_VM(0);
    bf16x8 xv = __builtin_bit_cast(bf16x8, dreg);
    float part[16];
#pragma unroll
    for (int o = 0; o < 16; ++o) part[o] = 0.f;
#pragma unroll
    for (int j = 0; j < 8; ++j) {
      float x = (float)xv[j];
      const float* wrow = fcW + (size_t)(lane * 8 + j) * 16;
#pragma unroll
      for (int o = 0; o < 16; ++o) part[o] = fmaf(x, wrow[o], part[o]);
    }
    __syncthreads();
    float* fl = reinterpret_cast<float*>(smem);
#pragma unroll
    for (int o = 0; o < 16; ++o) fl[lane * 17 + o] = part[o];
    __syncthreads();
    if (lane < 16) {
      float s = fcb[lane];
      for (int l = 0; l < 64; ++l) s += fl[l * 17 + lane];
      fl[64 * 17 + lane] = s;
    }
    __syncthreads();
    const int quad = lane >> 4;
    const float val = fl[64 * 17 + (lane & 15)];
    float* orow = out + (size_t)wgid * 768;
#pragma unroll
    for (int rep = 0; rep < 12; ++rep) {
      orow[(rep * 4 + quad) * 16 + (lane & 15)] = val;
    }
  }
}

// ---------------- launch ----------------
extern "C" void kernel_launch(void* const* d_in, const int* in_sizes, int n_in,
                              void* d_out, int out_size, void* d_ws, size_t ws_size,
                              hipStream_t stream) {
  (void)in_sizes; (void)n_in; (void)out_size; (void)ws_size;
  const float* inp = (const float*)d_in[0];
  // d_in[1] = future_seq_len (48, hardcoded)
  const float* eW0 = (const float*)d_in[2];
  const float* eU0 = (const float*)d_in[3];
  const float* eb0 = (const float*)d_in[4];
  const float* eW1 = (const float*)d_in[5];
  const float* eU1 = (const float*)d_in[6];
  const float* eb1 = (const float*)d_in[7];
  const float* dW0 = (const float*)d_in[8];
  const float* dU0 = (const float*)d_in[9];
  const float* db0 = (const float*)d_in[10];
  const float* dW1 = (const float*)d_in[11];
  const float* dU1 = (const float*)d_in[12];
  const float* db1 = (const float*)d_in[13];
  const float* fcW = (const float*)d_in[14];
  const float* fcb = (const float*)d_in[15];
  unsigned char* ws = (unsigned char*)d_ws;
  float* out = (float*)d_out;

  // zero h double-buffer + barrier counters (contiguous region)
  hipMemsetAsync(ws + OFF_HB, 0, HB_BYTES + CTR_BYTES, stream);

  lstm_main<<<dim3(256), dim3(64), 0, stream>>>(
      inp, eW0, eU0, eb0, eW1, eU1, eb1, dW0, dU0, db0, dW1, dU1, db1,
      fcW, fcb, ws, out);
}

// Round 5
// 2490.521 us; speedup vs baseline: 1.6579x; 1.3513x over previous
//
#include <hip/hip_runtime.h>

typedef __bf16 bf16;
typedef __bf16 bf16x8 __attribute__((ext_vector_type(8)));
typedef float  f32x16 __attribute__((ext_vector_type(16)));
typedef unsigned int u32x4 __attribute__((ext_vector_type(4)));

// ---------------- ws layout (bytes) ----------------
#define OFF_RW      0ull                 // rearranged weights, bf16 (12910592 B)
// h double buffer, block layout: [buf2][group8][producer32][row32][col16] bf16
#define OFF_HB      12910592ull
#define HB_BYTES    524288ull
#define OFF_FLAGS   13434880ull          // 8 groups x 32 producer flags (u32) = 1024 B
#define OFF_DCTR    13435904ull          // device barrier counter (64 B line)
#define OFF_Y0      21824512ull          // y0 [128][256][512] bf16 = 32 MB

// elem offsets into rW (bf16 elems); K-prefix {0,64,576,1088,1600,1616,2128,2640}
#define EO_W0   0
#define EO_U0   131072
#define EO_W1   1179648
#define EO_U1   2228224
#define EO_DW0  3276800
#define EO_DU0  3309568
#define EO_DW1  4358144
#define EO_DU1  5406720   // holds (dW1 + dU1) combined (dec1: x == h_init)

// ---------------- activations ----------------
__device__ __forceinline__ float fsig(float x) {
  x = fminf(fmaxf(x, -30.f), 30.f);
  float e = __builtin_amdgcn_exp2f(x * -1.4426950408889634f);
  return __builtin_amdgcn_rcpf(1.0f + e);
}
__device__ __forceinline__ float ftanh(float x) {
  x = fminf(fmaxf(x, -15.f), 15.f);
  float e = __builtin_amdgcn_exp2f(x * -2.8853900817779268f);
  return (1.0f - e) * __builtin_amdgcn_rcpf(1.0f + e);
}

// sc1 (agent-coherent / LLC) memory ops
#define HLOAD16(dst, addr) \
  asm volatile("global_load_dwordx4 %0, %1, off sc1" : "=v"(dst) : "v"(addr) : "memory")
#define HSTORE2(addr, val) \
  asm volatile("global_store_short %0, %1, off sc1" :: "v"(addr), "v"(val) : "memory")
#define HSTORE16(addr, val) \
  asm volatile("global_store_dwordx4 %0, %1, off sc1" :: "v"(addr), "v"(val) : "memory")
#define WAIT_VM(n) asm volatile("s_waitcnt vmcnt(" #n ")" ::: "memory")

// ---------------- main persistent kernel ----------------
// grid 256 wgs x 64 thr; wg -> (group g = blk&7 [32 batch rows], nc = blk>>3 [16 h-cols])
__global__ void __launch_bounds__(64, 1)
lstm_main(const float* __restrict__ inp,
          const float* __restrict__ eW0, const float* __restrict__ eU0, const float* __restrict__ eb0,
          const float* __restrict__ eW1, const float* __restrict__ eU1, const float* __restrict__ eb1,
          const float* __restrict__ dW0, const float* __restrict__ dU0, const float* __restrict__ db0,
          const float* __restrict__ dW1, const float* __restrict__ dU1, const float* __restrict__ db1,
          const float* __restrict__ fcW, const float* __restrict__ fcb,
          unsigned char* __restrict__ ws, float* __restrict__ out)
{
  __shared__ __align__(16) unsigned char smem[65536];

  const int wgid = blockIdx.x;
  const int g    = wgid & 7;
  const int nc   = wgid >> 3;
  const int lane = threadIdx.x;
  const int rowbase = g * 32;
  const int col32 = lane & 31;
  const int khalf = lane >> 5;
  const int half  = col32 >> 4;
  const int rowA  = rowbase + col32;

  const bf16* rW = reinterpret_cast<const bf16*>(ws + OFF_RW);
  bf16* hb  = reinterpret_cast<bf16*>(ws + OFF_HB);
  unsigned* flags = reinterpret_cast<unsigned*>(ws + OFF_FLAGS) + g * 32;
  unsigned* dctr  = reinterpret_cast<unsigned*>(ws + OFF_DCTR);
  bf16* y0  = reinterpret_cast<bf16*>(ws + OFF_Y0);

  unsigned depoch = 0;
  auto dbarrier = [&]() {
    depoch++;
    WAIT_VM(0);
    if (lane == 0) __hip_atomic_fetch_add(dctr, 1u, __ATOMIC_RELAXED, __HIP_MEMORY_SCOPE_AGENT);
    const unsigned tgt = depoch * 256u;
    while (__hip_atomic_load(dctr, __ATOMIC_RELAXED, __HIP_MEMORY_SCOPE_AGENT) < tgt)
      __builtin_amdgcn_s_sleep(1);
  };

  // ================= inline prep: weights -> MFMA B-fragment order (sc1 stores) ====
  {
    const int Ks[8]    = {64, 512, 512, 512, 16, 512, 512, 512};
    const int pref[8]  = {0, 64, 576, 1088, 1600, 1616, 2128, 2640};
    const float* srcs[8] = {eW0, eU0, eW1, eU1, dW0, dU0, dW1, dU1};
    bf16* rWw = reinterpret_cast<bf16*>(ws + OFF_RW);
    for (int base = 0; base < 3152; base += 64) {
      if (base + lane < 3152) {
        unsigned uid = (unsigned)wgid * 3152u + (unsigned)(base + lane);
        int m = 0;
#pragma unroll
        for (int i = 1; i < 8; ++i) if (uid >= (unsigned)pref[i] * 256u) m = i;
        unsigned local = uid - (unsigned)pref[m] * 256u;
        const int K = Ks[m];
        const unsigned perNC   = (unsigned)K * 8u;
        const unsigned ncb     = local / perNC;
        const unsigned r0      = local % perNC;
        const unsigned perTile = perNC >> 1;
        const unsigned ntile   = r0 / perTile;
        const unsigned r1      = r0 % perTile;
        const unsigned kstep   = r1 >> 6;
        const unsigned ln      = r1 & 63u;
        const unsigned c32     = ln & 31u;
        const unsigned gate    = ntile * 2u + (c32 >> 4);
        const unsigned zcol    = gate * 512u + ncb * 16u + (c32 & 15u);
        const unsigned kb      = kstep * 16u + (ln >> 5) * 8u;
        const float* s = srcs[m];
        bf16x8 v;
#pragma unroll
        for (int j = 0; j < 8; ++j) {
          float vj = s[(size_t)(kb + j) * 2048u + zcol];
          if (m == 7) vj += dW1[(size_t)(kb + j) * 2048u + zcol];  // dec1 combined W+U
          v[j] = (bf16)vj;
        }
        u32x4 bits = __builtin_bit_cast(u32x4, v);
        HSTORE16(rWw + (size_t)uid * 8, bits);
      }
    }
  }
  dbarrier();
  __builtin_amdgcn_fence(__ATOMIC_ACQUIRE, "agent");  // one-time: purge stale L1/L2

  // bias registers (gate pair [i|f] -> a, [g|o] -> b)
  const int bcol = nc * 16 + (col32 & 15);
  const int bg_  = col32 >> 4;
  const float bE0a = eb0[bg_ * 512 + bcol], bE0b = eb0[(2 + bg_) * 512 + bcol];
  const float bE1a = eb1[bg_ * 512 + bcol], bE1b = eb1[(2 + bg_) * 512 + bcol];
  const float bD0a = db0[bg_ * 512 + bcol], bD0b = db0[(2 + bg_) * 512 + bcol];
  const float bD1a = db1[bg_ * 512 + bcol], bD1b = db1[(2 + bg_) * 512 + bcol];

  float c[16];
#pragma unroll
  for (int i = 0; i < 16; ++i) c[i] = 0.f;

  auto load_lds = [&](const bf16* src) {
#pragma unroll 8
    for (int i = 0; i < 64; ++i) {
      *reinterpret_cast<bf16x8*>(smem + (i * 64 + lane) * 16) =
        *reinterpret_cast<const bf16x8*>(src + (size_t)(i * 64 + lane) * 8);
    }
    __syncthreads();
  };

  // ---- one recurrent step s (1-indexed): poll flags >= s-1, h GEMM vs LDS U,
  //      gates, h store to buffer s&1, publish flag = s. ----
  auto rec_step = [&](f32x16& a0, f32x16& a1, int s, bf16* ydst) {
    // decentralized group barrier: lane l polls producer l's flag
    if (lane < 32) {
      while (__hip_atomic_load(flags + lane, __ATOMIC_RELAXED, __HIP_MEMORY_SCOPE_AGENT)
             < (unsigned)(s - 1)) { }
    }
    // pipelined sc1 h loads from buffer (s-1)&1, block layout
    const char* hp = (const char*)hb + (size_t)((s - 1) & 1) * 262144 + (size_t)g * 32768
                     + (lane & 31) * 32 + khalf * 16;
    u32x4 hreg[16];
#pragma unroll
    for (int i = 0; i < 16; ++i) HLOAD16(hreg[i], hp + i * 1024);
#pragma unroll
    for (int b = 0; b < 4; ++b) {
      if (b < 3) { WAIT_VM(8); } else { WAIT_VM(0); }
      const int sb = (b & 1) * 8;
#pragma unroll
      for (int i = 0; i < 8; ++i) {
        const int ks = b * 8 + i;
        bf16x8 af  = __builtin_bit_cast(bf16x8, hreg[sb + i]);
        bf16x8 bl0 = *reinterpret_cast<const bf16x8*>(smem + (ks * 64 + lane) * 16);
        bf16x8 bl1 = *reinterpret_cast<const bf16x8*>(smem + 32768 + (ks * 64 + lane) * 16);
        a0 = __builtin_amdgcn_mfma_f32_32x32x16_bf16(af, bl0, a0, 0, 0, 0);
        a1 = __builtin_amdgcn_mfma_f32_32x32x16_bf16(af, bl1, a1, 0, 0, 0);
      }
      if (b < 2) {
#pragma unroll
        for (int i = 0; i < 8; ++i) HLOAD16(hreg[sb + i], hp + (16 + b * 8 + i) * 1024);
      }
    }
    // gates: a0 = [i|f] cols, a1 = [g|o] cols; partner gate via shfl_xor 16.
    bf16* hdst = hb + (size_t)(s & 1) * 131072 + (size_t)g * 16384 + (size_t)nc * 512;
#pragma unroll
    for (int r = 0; r < 16; ++r) {
      float v0 = a0[r], v1 = a1[r];
      float v0x = __shfl_xor(v0, 16, 64);
      float v1x = __shfl_xor(v1, 16, 64);
      float iv = half ? v0x : v0;
      float fv = half ? v0  : v0x;
      float gv = half ? v1x : v1;
      float ov = half ? v1  : v1x;
      float cn = fsig(fv) * c[r] + fsig(iv) * ftanh(gv);
      c[r] = cn;
      float hv = fsig(ov) * ftanh(cn);
      if (half == 0) {
        int row = (r & 3) + 8 * (r >> 2) + 4 * khalf;
        unsigned short hbits = __builtin_bit_cast(unsigned short, (bf16)hv);
        HSTORE2(hdst + row * 16 + col32, hbits);
        if (ydst) HSTORE2(ydst + (size_t)(rowbase + row) * 512 + nc * 16 + col32, hbits);
      }
    }
    // publish: drain stores, then flag := s (plain sc1 dword, producer-owned)
    WAIT_VM(0);
    if (lane == 0)
      __hip_atomic_store(flags + nc, (unsigned)s, __ATOMIC_RELAXED, __HIP_MEMORY_SCOPE_AGENT);
  };

  // x-projection for a 4-step chunk; acc stays in VGPRs
  auto xproj = [&](int isPh1, int ch, const bf16* rX, int kxs, float bza, float bzb,
                   f32x16 (&acc)[4][2]) {
#pragma unroll
    for (int tt = 0; tt < 4; ++tt)
#pragma unroll
      for (int r = 0; r < 16; ++r) { acc[tt][0][r] = bza; acc[tt][1][r] = bzb; }
    for (int ks = 0; ks < kxs; ++ks) {
      bf16x8 bg0 = *reinterpret_cast<const bf16x8*>(rX + (size_t)ks * 512 + lane * 8);
      bf16x8 bg1 = *reinterpret_cast<const bf16x8*>(rX + (size_t)(kxs + ks) * 512 + lane * 8);
#pragma unroll
      for (int tt = 0; tt < 4; ++tt) {
        const int t = ch * 4 + tt;
        bf16x8 af;
        if (isPh1) {
          af = *reinterpret_cast<const bf16x8*>(y0 + ((size_t)t * 256 + rowA) * 512 + ks * 16 + khalf * 8);
        } else {
          const float* p = inp + ((size_t)rowA * 128 + t) * 64 + ks * 16 + khalf * 8;
#pragma unroll
          for (int j = 0; j < 8; ++j) af[j] = (bf16)p[j];
        }
        acc[tt][0] = __builtin_amdgcn_mfma_f32_32x32x16_bf16(af, bg0, acc[tt][0], 0, 0, 0);
        acc[tt][1] = __builtin_amdgcn_mfma_f32_32x32x16_bf16(af, bg1, acc[tt][1], 0, 0, 0);
      }
    }
  };

  const bf16* rU0e = rW + EO_U0 + (size_t)nc * 32768;
  const bf16* rU1e = rW + EO_U1 + (size_t)nc * 32768;
  const bf16* rX0e = rW + EO_W0 + (size_t)nc * 4096;
  const bf16* rX1e = rW + EO_W1 + (size_t)nc * 32768;

  // ================= encoder layers =================
  f32x16 acc[4][2];
  load_lds(rU0e);
  xproj(0, 0, rX0e, 4, bE0a, bE0b, acc);
  int s = 1;
  for (int ph = 0; ph < 2; ++ph) {
    for (int ch = 0; ch < 32; ++ch) {
#pragma unroll
      for (int tt = 0; tt < 4; ++tt) {
        rec_step(acc[tt][0], acc[tt][1], s,
                 (ph == 0) ? (y0 + (size_t)(ch * 4 + tt) * 131072) : nullptr);
        if (tt == 3) {                       // fill the inter-step window
          if (ch < 31) {
            if (ph == 0) xproj(0, ch + 1, rX0e, 4,  bE0a, bE0b, acc);
            else         xproj(1, ch + 1, rX1e, 32, bE1a, bE1b, acc);
          } else if (ph == 0) {
            load_lds(rU1e);
            xproj(1, 0, rX1e, 32, bE1a, bE1b, acc);
          } else {
            load_lds(rW + EO_DU0 + (size_t)nc * 32768);   // stage decoder0 U
          }
        }
        s++;
      }
    }
  }

  // ================= decoder layer 0 (1 step, Kx=16) =================
  {
    f32x16 a0, a1;
#pragma unroll
    for (int r = 0; r < 16; ++r) { a0[r] = bD0a; a1[r] = bD0b; }
    const bf16* rX = rW + EO_DW0 + (size_t)nc * 1024;
    bf16x8 bg0 = *reinterpret_cast<const bf16x8*>(rX + lane * 8);
    bf16x8 bg1 = *reinterpret_cast<const bf16x8*>(rX + 512 + lane * 8);
    bf16x8 af;
    const float* p = inp + ((size_t)rowA * 128 + 127) * 64 + khalf * 8;  // inp[:,-1,:16]
#pragma unroll
    for (int j = 0; j < 8; ++j) af[j] = (bf16)p[j];
    a0 = __builtin_amdgcn_mfma_f32_32x32x16_bf16(af, bg0, a0, 0, 0, 0);
    a1 = __builtin_amdgcn_mfma_f32_32x32x16_bf16(af, bg1, a1, 0, 0, 0);
    rec_step(a0, a1, s, nullptr);
    load_lds(rW + EO_DU1 + (size_t)nc * 32768);   // combined (dW1+dU1)
    s++;
  }

  // ================= decoder layer 1: z = d0 @ (dW1+dU1) + b (x == h_init) ========
  {
    f32x16 a0, a1;
#pragma unroll
    for (int r = 0; r < 16; ++r) { a0[r] = bD1a; a1[r] = bD1b; }
    rec_step(a0, a1, s, nullptr);   // s = 258
  }

  // cross-group visibility for FC (wg reads batch row wgid, produced by another group)
  dbarrier();

  // ================= FC + tile(48) : wg handles batch row = wgid =================
  {
    // d1 row=wgid in block layout: group wgid>>5, producer lane>>1, row wgid&31
    const char* dp = (const char*)hb + (size_t)(258 & 1) * 262144
                     + (size_t)(wgid >> 5) * 32768 + (lane >> 1) * 1024
                     + (wgid & 31) * 32 + (lane & 1) * 16;
    u32x4 dreg;
    HLOAD16(dreg, dp);
    WAIT_VM(0);
    bf16x8 xv = __builtin_bit_cast(bf16x8, dreg);
    float part[16];
#pragma unroll
    for (int o = 0; o < 16; ++o) part[o] = 0.f;
#pragma unroll
    for (int j = 0; j < 8; ++j) {
      float x = (float)xv[j];
      const float* wrow = fcW + (size_t)(lane * 8 + j) * 16;
#pragma unroll
      for (int o = 0; o < 16; ++o) part[o] = fmaf(x, wrow[o], part[o]);
    }
    __syncthreads();
    float* fl = reinterpret_cast<float*>(smem);
#pragma unroll
    for (int o = 0; o < 16; ++o) fl[lane * 17 + o] = part[o];
    __syncthreads();
    if (lane < 16) {
      float sum = fcb[lane];
      for (int l = 0; l < 64; ++l) sum += fl[l * 17 + lane];
      fl[64 * 17 + lane] = sum;
    }
    __syncthreads();
    const int quad = lane >> 4;
    const float val = fl[64 * 17 + (lane & 15)];
    float* orow = out + (size_t)wgid * 768;
#pragma unroll
    for (int rep = 0; rep < 12; ++rep) {
      orow[(rep * 4 + quad) * 16 + (lane & 15)] = val;
    }
  }
}

// ---------------- launch ----------------
extern "C" void kernel_launch(void* const* d_in, const int* in_sizes, int n_in,
                              void* d_out, int out_size, void* d_ws, size_t ws_size,
                              hipStream_t stream) {
  (void)in_sizes; (void)n_in; (void)out_size; (void)ws_size;
  const float* inp = (const float*)d_in[0];
  // d_in[1] = future_seq_len (48, hardcoded)
  const float* eW0 = (const float*)d_in[2];
  const float* eU0 = (const float*)d_in[3];
  const float* eb0 = (const float*)d_in[4];
  const float* eW1 = (const float*)d_in[5];
  const float* eU1 = (const float*)d_in[6];
  const float* eb1 = (const float*)d_in[7];
  const float* dW0 = (const float*)d_in[8];
  const float* dU0 = (const float*)d_in[9];
  const float* db0 = (const float*)d_in[10];
  const float* dW1 = (const float*)d_in[11];
  const float* dU1 = (const float*)d_in[12];
  const float* db1 = (const float*)d_in[13];
  const float* fcW = (const float*)d_in[14];
  const float* fcb = (const float*)d_in[15];
  unsigned char* ws = (unsigned char*)d_ws;
  float* out = (float*)d_out;

  // zero h double-buffer + flags + device counter (contiguous region)
  hipMemsetAsync(ws + OFF_HB, 0, HB_BYTES + 1024 + 64, stream);

  lstm_main<<<dim3(256), dim3(64), 0, stream>>>(
      inp, eW0, eU0, eb0, eW1, eU1, eb1, dW0, dU0, db0, dW1, dU1, db1,
      fcW, fcb, ws, out);
}